// Round 15
// baseline (322.538 us; speedup 1.0000x reference)
//
#include <hip/hip_runtime.h>
#include <cstdint>

#define NA 20000
#define NE 80000

typedef __attribute__((ext_vector_type(8))) short short8;
typedef __attribute__((ext_vector_type(4))) float f32x4;
typedef unsigned short ushort_t;

// per-l offsets (in ELEMENTS) inside h / out buffers (atom-major, [n][i][j][c])
constexpr int HOFFc[4]   = {0, 2560000, 5120000, 10880000};
// packed rbm layout per edge: rbm0[128] rbm1[96] rbm2[64] rbm3[32]  (320 total)
constexpr int RBMOFFc[4] = {0, 128, 224, 288};

__device__ __forceinline__ ushort_t f2bf(float x) {
    union { float f; unsigned u; } v; v.f = x;
    unsigned r = v.u + 0x7fffu + ((v.u >> 16) & 1u);
    return (ushort_t)(r >> 16);
}
__device__ __forceinline__ float bf2f(ushort_t u) {
    union { unsigned u; float f; } v; v.u = ((unsigned)u) << 16;
    return v.f;
}
__device__ __forceinline__ unsigned pack2(float a, float b) {
    return ((unsigned)f2bf(b) << 16) | (unsigned)f2bf(a);
}

// ---------------- fused: edge-histogram + one-time weight prep ----------------
__global__ __launch_bounds__(256)
void k_hist_prep(const int* __restrict__ centers, int* __restrict__ counts,
                 const float* __restrict__ B0, const float* __restrict__ B1,
                 const float* __restrict__ B2, const float* __restrict__ B3,
                 const float* __restrict__ A, const float* __restrict__ Win,
                 ushort_t* __restrict__ BT, ushort_t* __restrict__ ATb,
                 ushort_t* __restrict__ WinTb)
{
    const int b = blockIdx.x;
    if (b < 313) {
        const int e = b * 256 + threadIdx.x;
        if (e < NE) atomicAdd(&counts[centers[e]], 1);
        return;
    }
    const int i = (b - 313) * 256 + threadIdx.x;
    if (i < 40960) {
        const int n = i >> 7, k = i & 127;
        const float* src; int nl, N;
        if (n < 128)      { src = B0; nl = n;       N = 128; }
        else if (n < 224) { src = B1; nl = n - 128; N = 96;  }
        else if (n < 288) { src = B2; nl = n - 224; N = 64;  }
        else              { src = B3; nl = n - 288; N = 32;  }
        BT[i] = f2bf(src[k * N + nl]);
    } else if (i < 57344) {
        const int j2 = i - 40960;
        const int l = j2 >> 12, rem = j2 & 4095, jrow = rem >> 5, k = rem & 31;
        ATb[j2] = f2bf(A[l * 4096 + k * 128 + jrow]);
    } else if (i < 61440) {
        const int j3 = i - 57344;
        const int l = j3 >> 10, rem = j3 & 1023, g = rem >> 5, k = rem & 31;
        WinTb[j3] = f2bf(Win[l * 1024 + k * 32 + g]);
    }
}

// ---------------- norm body: RMSNorm + linear_in via MFMA -> h (bf16) ----------------
template<int S, int AB>
__device__ __forceinline__ void norm_body(
    int bx, const float* __restrict__ fsel, const float* __restrict__ gammas, int l,
    const ushort_t* __restrict__ WinTb, ushort_t* __restrict__ hb,
    ushort_t* __restrict__ s_wt, float* __restrict__ s_scale)
{
    const int t = threadIdx.x;
    const int na0 = bx * AB;

    if (t < 128) {
        reinterpret_cast<uint4*>(s_wt)[t] =
            reinterpret_cast<const uint4*>(WinTb + l * 1024)[t];
    }
    for (int i = t; i < AB * 32; i += 256) {
        const int a = i >> 5, c = i & 31;
        int aa = na0 + a; if (aa > NA - 1) aa = NA - 1;
        const float* fp = fsel + ((size_t)aa * S) * 32 + c;
        float ss = 0.f;
        #pragma unroll
        for (int s = 0; s < S; ++s) { const float v = fp[s * 32]; ss += v * v; }
        s_scale[i] = gammas[l * 32 + c] * rsqrtf(ss / (float)S + 1e-6f);
    }
    __syncthreads();

    const int w = t >> 6, lane = t & 63, l15 = lane & 15, lg = lane >> 4;
    const int row = w * 16 + l15;
    const bool rvalid = row < AB * S;
    const int rowc = rvalid ? row : 0;
    const int a = rowc / S, s = rowc % S;
    const int atom = na0 + a;
    const bool store_ok = rvalid && (atom < NA);
    const int atomc = (atom < NA) ? atom : (NA - 1);

    const float* fp = fsel + ((size_t)atomc * S + s) * 32 + lg * 8;
    const float4 x0 = *reinterpret_cast<const float4*>(fp);
    const float4 x1 = *reinterpret_cast<const float4*>(fp + 4);
    const float4 c0 = *reinterpret_cast<const float4*>(&s_scale[a * 32 + lg * 8]);
    const float4 c1 = *reinterpret_cast<const float4*>(&s_scale[a * 32 + lg * 8 + 4]);

    union { short8 v; unsigned u[4]; } bf;
    bf.u[0] = pack2(x0.x * c0.x, x0.y * c0.y);
    bf.u[1] = pack2(x0.z * c0.z, x0.w * c0.w);
    bf.u[2] = pack2(x1.x * c1.x, x1.y * c1.y);
    bf.u[3] = pack2(x1.z * c1.z, x1.w * c1.w);

    const short8 a0 = *reinterpret_cast<const short8*>(&s_wt[l15 * 32 + lg * 8]);
    const short8 a1 = *reinterpret_cast<const short8*>(&s_wt[(16 + l15) * 32 + lg * 8]);
    f32x4 d0 = __builtin_amdgcn_mfma_f32_16x16x32_bf16(a0, bf.v, (f32x4){0.f,0.f,0.f,0.f}, 0, 0, 0);
    f32x4 d1 = __builtin_amdgcn_mfma_f32_16x16x32_bf16(a1, bf.v, (f32x4){0.f,0.f,0.f,0.f}, 0, 0, 0);

    if (store_ok) {
        ushort_t* hp = hb + ((size_t)atomc * S + s) * 32;
        uint2 o0; o0.x = pack2(d0[0], d0[1]); o0.y = pack2(d0[2], d0[3]);
        uint2 o1; o1.x = pack2(d1[0], d1[1]); o1.y = pack2(d1[2], d1[3]);
        *reinterpret_cast<uint2*>(&hp[0  + 4 * lg]) = o0;
        *reinterpret_cast<uint2*>(&hp[16 + 4 * lg]) = o1;
    }
}

// ---------------- edge body: radial MLP, both phases MFMA ----------------
__device__ __forceinline__ void edge_body(
    int l, int e0,
    const float* __restrict__ rb,
    const float* __restrict__ sh0, const float* __restrict__ sh1,
    const float* __restrict__ sh2, const float* __restrict__ sh3,
    const ushort_t* __restrict__ BT, const ushort_t* __restrict__ ATb,
    ushort_t* __restrict__ rbm, float* __restrict__ shq,
    ushort_t* __restrict__ smem)
{
    ushort_t* s_h  = smem;            // [64][128] bf16 swizzled (16 KB)
    ushort_t* s_r2 = smem + 8192;     // 32 KB region
    ushort_t* s_rbbf = s_r2;          // [64][32]
    ushort_t* s_at   = s_r2 + 2048;   // [128][32]
    ushort_t* s_bt   = s_r2;          // [N_l][128] swizzled (phase2)

    const int t = threadIdx.x;
    const int w = t >> 6, lane = t & 63;
    const int l15 = lane & 15, lg = lane >> 4;

    if (l == 0) {
        for (int i = t; i < 1024; i += 256) {
            const int q = i & 15, ge = e0 + (i >> 4);
            float v;
            if (q == 0)      v = sh0[ge];
            else if (q < 4)  v = sh1[ge * 3 + (q - 1)];
            else if (q < 9)  v = sh2[ge * 5 + (q - 4)];
            else             v = sh3[ge * 7 + (q - 9)];
            shq[(size_t)e0 * 16 + i] = v;
        }
    }

    const int Kl[4] = {128, 96, 64, 32};
    const int erow = w * 16 + l15;

    for (int i = t; i < 1024; i += 256) {
        const float2 v = *reinterpret_cast<const float2*>(
            &rb[(size_t)l * NE * 32 + (size_t)e0 * 32 + 2 * i]);
        *reinterpret_cast<unsigned*>(&s_rbbf[2 * i]) = pack2(v.x, v.y);
    }
    {
        const uint4* src = reinterpret_cast<const uint4*>(ATb + (size_t)l * 4096);
        for (int i = t; i < 512; i += 256) reinterpret_cast<uint4*>(s_at)[i] = src[i];
    }
    __syncthreads();

    // phase1 MFMA: hid = rb @ A_l -> s_h (swizzled bf16)
    const short8 rbf = *reinterpret_cast<const short8*>(&s_rbbf[erow * 32 + lg * 8]);
    #pragma unroll
    for (int jt = 0; jt < 8; ++jt) {
        const short8 af = *reinterpret_cast<const short8*>(&s_at[(jt * 16 + l15) * 32 + lg * 8]);
        f32x4 d = __builtin_amdgcn_mfma_f32_16x16x32_bf16(af, rbf, (f32x4){0.f,0.f,0.f,0.f}, 0, 0, 0);
        float s0 = d[0] / (1.f + __expf(-d[0]));
        float s1 = d[1] / (1.f + __expf(-d[1]));
        float s2 = d[2] / (1.f + __expf(-d[2]));
        float s3 = d[3] / (1.f + __expf(-d[3]));
        const int chunk = jt * 2 + (lg >> 1);
        const int base = erow * 128 + ((chunk ^ (erow & 7)) << 3) + (lg & 1) * 4;
        uint2 ov; ov.x = pack2(s0, s1); ov.y = pack2(s2, s3);
        *reinterpret_cast<uint2*>(&s_h[base]) = ov;
    }
    __syncthreads();

    // stage B^T_l
    const int K = Kl[l];
    for (int cch = t; cch < (K << 4); cch += 256) {
        const int n = cch >> 4, loc = cch & 15;
        const uint4 v = *reinterpret_cast<const uint4*>(&BT[(size_t)(RBMOFFc[l] + n) * 128 + loc * 8]);
        *reinterpret_cast<uint4*>(&s_bt[n * 128 + ((loc ^ (n & 7)) << 3)]) = v;
    }
    __syncthreads();

    // phase2 MFMA: rbm[e][n]
    const short8 hf0 = *reinterpret_cast<const short8*>(&s_h[erow * 128 + (((0 + lg) ^ (erow & 7)) << 3)]);
    const short8 hf1 = *reinterpret_cast<const short8*>(&s_h[erow * 128 + (((4 + lg) ^ (erow & 7)) << 3)]);
    const short8 hf2 = *reinterpret_cast<const short8*>(&s_h[erow * 128 + (((8 + lg) ^ (erow & 7)) << 3)]);
    const short8 hf3 = *reinterpret_cast<const short8*>(&s_h[erow * 128 + (((12 + lg) ^ (erow & 7)) << 3)]);

    const int ntn = K >> 4;
    for (int nt = 0; nt < ntn; ++nt) {
        const int n = nt * 16 + l15;
        f32x4 acc = {0.f, 0.f, 0.f, 0.f};
        #pragma unroll
        for (int ks = 0; ks < 4; ++ks) {
            const short8 af = *reinterpret_cast<const short8*>(
                &s_bt[n * 128 + (((ks * 4 + lg) ^ (n & 7)) << 3)]);
            const short8 hfk = (ks == 0) ? hf0 : (ks == 1) ? hf1 : (ks == 2) ? hf2 : hf3;
            acc = __builtin_amdgcn_mfma_f32_16x16x32_bf16(af, hfk, acc, 0, 0, 0);
        }
        uint2 ov;
        ov.x = pack2(acc[0], acc[1]);
        ov.y = pack2(acc[2], acc[3]);
        *reinterpret_cast<uint2*>(&rbm[(size_t)(e0 + erow) * 320 + RBMOFFc[l] + nt * 16 + 4 * lg]) = ov;
    }
}

// ---------------- ONE mid dispatch: edge blocks [0,5000), norm blocks [5000,15358) ----------------
__global__ __launch_bounds__(256, 3)
void k_ne(const float* __restrict__ rb,
          const float* __restrict__ sh0, const float* __restrict__ sh1,
          const float* __restrict__ sh2, const float* __restrict__ sh3,
          const float* __restrict__ f0, const float* __restrict__ f1,
          const float* __restrict__ f2, const float* __restrict__ f3,
          const float* __restrict__ gammas,
          const ushort_t* __restrict__ BT, const ushort_t* __restrict__ ATb,
          const ushort_t* __restrict__ WinTb,
          ushort_t* __restrict__ rbm, float* __restrict__ shq,
          ushort_t* __restrict__ h)
{
    __shared__ ushort_t smem[24576];   // 48 KB union
    const int b = blockIdx.x;
    if (b < 5000) {
        edge_body(b / 1250, (b % 1250) * 64, rb, sh0, sh1, sh2, sh3,
                  BT, ATb, rbm, shq, smem);
        return;
    }
    ushort_t* s_wt   = smem;                                   // 1024 ush
    float*    s_scale = reinterpret_cast<float*>(smem + 1024); // 512 f
    const int nb = b - 5000;
    if (nb < 1250)       norm_body<4, 16>(nb,        f0, gammas, 0, WinTb, h + HOFFc[0], s_wt, s_scale);
    else if (nb < 2500)  norm_body<4, 16>(nb - 1250, f1, gammas, 1, WinTb, h + HOFFc[1], s_wt, s_scale);
    else if (nb < 5358)  norm_body<9, 7>(nb - 2500,  f2, gammas, 2, WinTb, h + HOFFc[2], s_wt, s_scale);
    else                 norm_body<16, 4>(nb - 5358, f3, gammas, 3, WinTb, h + HOFFc[3], s_wt, s_scale);
}

// ---------------- CSR scan + fill ----------------
__global__ __launch_bounds__(1024)
void k_scan(const int* __restrict__ counts, int* __restrict__ offsets)
{
    __shared__ int s_sum[1024];
    const int t = threadIdx.x;
    const int CH = 20;
    const int base = t * CH;
    int n = NA - base; n = n < 0 ? 0 : (n > CH ? CH : n);

    int tot = 0;
    for (int i = 0; i < n; i++) tot += counts[base + i];
    s_sum[t] = tot;
    __syncthreads();
    for (int off = 1; off < 1024; off <<= 1) {
        int v = (t >= off) ? s_sum[t - off] : 0;
        __syncthreads();
        s_sum[t] += v;
        __syncthreads();
    }
    int run = s_sum[t] - tot;
    for (int i = 0; i < n; i++) { offsets[base + i] = run; run += counts[base + i]; }
    if (t == 0) offsets[NA] = NE;
}

__global__ __launch_bounds__(256)
void k_fill(const int* __restrict__ centers, const int* __restrict__ offsets,
            int* __restrict__ cursor, int* __restrict__ elist)
{
    const int e = blockIdx.x * 256 + threadIdx.x;
    if (e < NE) {
        const int ctr = centers[e];
        const int pos = offsets[ctr] + atomicAdd(&cursor[ctr], 1);
        elist[pos] = e;
    }
}

// ---------------- TP step (bf16 LDS h), all register indices compile-time ----------------
template<int P1, int ASTART, int ACNT>
__device__ __forceinline__ void tp_step(float* __restrict__ acc,
                                        const float* __restrict__ lg,
                                        const ushort_t* __restrict__ lh,
                                        const float* __restrict__ rv, int c)
{
    float un[ACNT];
    #pragma unroll
    for (int pi = 0; pi < ACNT; ++pi) {
        const int p = ASTART + pi;
        float a = 0.f;
        #pragma unroll
        for (int lp = 0; lp < P1; ++lp) a += lg[p * 4 + lp] * rv[lp];
        un[pi] = a;
    }
    #pragma unroll
    for (int ii = 0; ii < ACNT / P1; ++ii) {
        #pragma unroll
        for (int k = 0; k < P1; ++k) {
            float m = 0.f;
            #pragma unroll
            for (int j = 0; j < P1; ++j) m += un[ii * P1 + j] * bf2f(lh[(j * P1 + k) * 32 + c]);
            acc[ii * P1 + k] += m;
        }
    }
}

// ---------------- pool body: l2/l3 (paired edges), carving union LDS ----------------
template<int P1, int LOWER>
__device__ __forceinline__ void pool_big_body(
    const float* __restrict__ Up, float uscale,
    const float* __restrict__ WoutL, const float* __restrict__ msp,
    const float* __restrict__ shq, const ushort_t* __restrict__ rbm,
    const ushort_t* __restrict__ hL, const float* __restrict__ fL,
    float* __restrict__ outL,
    const int* __restrict__ offsets, const int* __restrict__ elist,
    const int* __restrict__ neighbors, float* __restrict__ sm)
{
    constexpr int S       = P1 * P1;
    constexpr int ACNT0   = (P1 == 4) ? 8 : 6;
    constexpr int ACNT1   = (P1 == 4) ? 8 : 3;
    constexpr int ASTART1 = ACNT0;
    constexpr int NV      = (S * 32) / 8;

    float*    s_U    = sm;
    float*    s_w    = sm + 256;
    ushort_t* s_hbuf = reinterpret_cast<ushort_t*>(sm + 256 + 1024);
    float*    s_gbuf = sm + 256 + 1024 + 128 * S;   // 8 bufs of S*32 ushorts = 128*S floats

    const int t = threadIdx.x;
    for (int i = t; i < S * S; i += 256) s_U[i] = Up[i] * uscale;
    for (int i = t; i < 1024; i += 256) s_w[i] = WoutL[i];
    __syncthreads();

    const int w = t >> 6, lane = t & 63, c = lane & 31, half = lane >> 5;
    const int n = blockIdx.x * 4 + w;
    const float ms = *msp;
    const int beg = offsets[n], end = offsets[n + 1];

    const int gp = lane >> 2, glp = lane & 3;
    const int qlo = (glp == 0) ? 0 : (glp == 1) ? 1 : (glp == 2) ? 4 : 9;
    const int qhi = (glp == 0) ? 1 : (glp == 1) ? 4 : (glp == 2) ? 9 : 16;
    const bool gvalid = (gp < S) && (glp < P1);

    float acc[ACNT0];
    #pragma unroll
    for (int x = 0; x < ACNT0; ++x) acc[x] = 0.f;

    ushort_t* lhA = s_hbuf + w * 2 * (S * 32);
    ushort_t* lhB = lhA + S * 32;
    float*    lgA = s_gbuf + w * 128;
    float*    lgB = lgA + 64;

    for (int slot = beg; slot < end; slot += 2) {
        const bool haveB = (slot + 1) < end;
        const int eA = elist[slot];
        const int eB = elist[haveB ? slot + 1 : slot];
        const int nbrA = neighbors[eA];
        const int nbrB = neighbors[eB];

        uint4 vA = {}, vB = {};
        const uint4* hpA = reinterpret_cast<const uint4*>(hL + (size_t)nbrA * (S * 32));
        const uint4* hpB = reinterpret_cast<const uint4*>(hL + (size_t)nbrB * (S * 32));
        if (lane < NV) { vA = hpA[lane]; vB = hpB[lane]; }

        const ushort_t* rrA = rbm + (size_t)eA * 320 + LOWER + c;
        const ushort_t* rrB = rbm + (size_t)eB * 320 + LOWER + c;
        float rvA[4], rvB[4];
        #pragma unroll
        for (int lp = 0; lp < P1; ++lp) { rvA[lp] = bf2f(rrA[RBMOFFc[lp]]); rvB[lp] = bf2f(rrB[RBMOFFc[lp]]); }

        const float* sqA = shq + (size_t)eA * 16;
        const float* sqB = shq + (size_t)eB * 16;
        float gA = 0.f, gB = 0.f;
        if (gvalid) {
            for (int q = qlo; q < qhi; ++q) {
                const float u = s_U[gp * S + q];
                gA += u * sqA[q];
                gB += u * sqB[q];
            }
        }

        if (lane < NV) {
            reinterpret_cast<uint4*>(lhA)[lane] = vA;
            reinterpret_cast<uint4*>(lhB)[lane] = vB;
        }
        lgA[lane] = gA;
        lgB[lane] = gB;

        asm volatile("s_waitcnt lgkmcnt(0)" ::: "memory");

        if (half == 0) tp_step<P1, 0,       ACNT0>(acc, lgA, lhA, rvA, c);
        else           tp_step<P1, ASTART1, ACNT1>(acc, lgA, lhA, rvA, c);
        if (haveB) {
            if (half == 0) tp_step<P1, 0,       ACNT0>(acc, lgB, lhB, rvB, c);
            else           tp_step<P1, ASTART1, ACNT1>(acc, lgB, lhB, rvB, c);
        }
    }

    float* accStage = reinterpret_cast<float*>(lhA);   // spans lhA+lhB = S*32 floats
    if (half == 0) {
        #pragma unroll
        for (int x = 0; x < ACNT0; ++x) accStage[x * 32 + c] = acc[x];
    } else {
        #pragma unroll
        for (int x = 0; x < ACNT1; ++x) accStage[(ASTART1 + x) * 32 + c] = acc[x];
    }
    asm volatile("s_waitcnt lgkmcnt(0)" ::: "memory");

    const float* fp = fL + (size_t)n * (S * 32);
    float* op = outL + (size_t)n * (S * 32);
    for (int s = half; s < S; s += 2) {
        float o = 0.f;
        #pragma unroll
        for (int f = 0; f < 32; f++) o += accStage[s * 32 + f] * s_w[f * 32 + c];
        op[s * 32 + c] = fp[s * 32 + c] + ms * o;
    }
}

// ---------------- pool body: fused l0+l1, carving union LDS ----------------
__device__ __forceinline__ void pool_01_body(
    const float* __restrict__ U1, const float* __restrict__ Wout,
    const float* __restrict__ msp, const float* __restrict__ shq,
    const ushort_t* __restrict__ rbm, const ushort_t* __restrict__ h,
    const float* __restrict__ f0, const float* __restrict__ f1,
    float* __restrict__ out,
    const int* __restrict__ offsets, const int* __restrict__ elist,
    const int* __restrict__ neighbors, float* __restrict__ sm)
{
    float* s_U   = sm;
    float* s_w   = sm + 16;
    float* s_acc = sm + 16 + 2048;

    const int t = threadIdx.x;
    if (t < 16) s_U[t] = U1[t] * 0.70710678118654752f;
    for (int i = t; i < 2048; i += 256) s_w[i] = Wout[i];
    __syncthreads();

    const int w = t >> 6, lane = t & 63, c = lane & 31, half = lane >> 5;
    const int n = blockIdx.x * 4 + w;
    const float ms = *msp;
    const int beg = offsets[n], end = offsets[n + 1];
    const ushort_t* h0 = h;
    const ushort_t* h1 = h + 2560000;

    float acc0[4] = {0.f, 0.f, 0.f, 0.f};
    float acc1[4] = {0.f, 0.f, 0.f, 0.f};

    const int nit = (end - beg + 1) >> 1;
    for (int it = 0; it < nit; ++it) {
        const int slot = beg + it * 2 + half;
        const bool valid = slot < end;
        const int e   = elist[valid ? slot : beg];
        const int nbr = neighbors[e];
        const float fac = valid ? 1.f : 0.f;

        const ushort_t* rrow = rbm + (size_t)e * 320;
        const float rv0  = fac * bf2f(rrow[96 + c]);
        const float rv1a = fac * bf2f(rrow[64 + c]);
        const float rv1b = fac * bf2f(rrow[192 + c]);
        const float* sqp = shq + (size_t)e * 16;
        const float sq0 = sqp[0], sq1 = sqp[1], sq2 = sqp[2], sq3 = sqp[3];

        float hn0[4], hn1[4];
        const ushort_t* hp0 = h0 + (size_t)nbr * 128 + c;
        const ushort_t* hp1 = h1 + (size_t)nbr * 128 + c;
        #pragma unroll
        for (int p = 0; p < 4; ++p) { hn0[p] = bf2f(hp0[p * 32]); hn1[p] = bf2f(hp1[p * 32]); }

        const float st0 = sq0 * rv0;
        float st1[4];
        st1[0] = sq0 * rv1a; st1[1] = sq1 * rv1b; st1[2] = sq2 * rv1b; st1[3] = sq3 * rv1b;

        float unc0[4], unc1[4];
        #pragma unroll
        for (int p = 0; p < 4; ++p) {
            unc0[p] = s_U[p * 4] * st0;
            float a = 0.f;
            #pragma unroll
            for (int q = 0; q < 4; ++q) a += s_U[p * 4 + q] * st1[q];
            unc1[p] = a;
        }
        #pragma unroll
        for (int i = 0; i < 2; ++i) {
            #pragma unroll
            for (int k = 0; k < 2; ++k) {
                float m0 = 0.f, m1 = 0.f;
                #pragma unroll
                for (int j = 0; j < 2; ++j) {
                    m0 += unc0[i * 2 + j] * hn0[j * 2 + k];
                    m1 += unc1[i * 2 + j] * hn1[j * 2 + k];
                }
                acc0[i * 2 + k] += m0;
                acc1[i * 2 + k] += m1;
            }
        }
    }

    #pragma unroll
    for (int s = 0; s < 4; s++) { acc0[s] += __shfl_xor(acc0[s], 32); acc1[s] += __shfl_xor(acc1[s], 32); }
    #pragma unroll
    for (int s = 0; s < 4; s++) if ((s & 1) == half) {
        s_acc[(w * 2 + 0) * 128 + s * 32 + c] = acc0[s];
        s_acc[(w * 2 + 1) * 128 + s * 32 + c] = acc1[s];
    }
    __syncthreads();

    const float* fp0 = f0 + (size_t)n * 128;
    const float* fp1 = f1 + (size_t)n * 128;
    float* op0 = out + (size_t)n * 128;
    float* op1 = out + 2560000 + (size_t)n * 128;
    for (int s = half; s < 4; s += 2) {
        float o0 = 0.f, o1 = 0.f;
        #pragma unroll
        for (int f = 0; f < 32; f++) {
            o0 += s_acc[(w * 2 + 0) * 128 + s * 32 + f] * s_w[f * 32 + c];
            o1 += s_acc[(w * 2 + 1) * 128 + s * 32 + f] * s_w[1024 + f * 32 + c];
        }
        op0[s * 32 + c] = fp0[s * 32 + c] + ms * o0;
        op1[s * 32 + c] = fp1[s * 32 + c] + ms * o1;
    }
}

// ---------------- ONE pool dispatch: blockIdx.y selects {l3, l2, l0+l1} ----------------
__global__ __launch_bounds__(256, 8)
void k_pools(const float* __restrict__ U1, const float* __restrict__ U2,
             const float* __restrict__ U3, const float* __restrict__ Wout,
             const float* __restrict__ msp, const float* __restrict__ shq,
             const ushort_t* __restrict__ rbm, const ushort_t* __restrict__ h,
             const float* __restrict__ f0, const float* __restrict__ f1,
             const float* __restrict__ f2, const float* __restrict__ f3,
             float* __restrict__ out,
             const int* __restrict__ offsets, const int* __restrict__ elist,
             const int* __restrict__ neighbors)
{
    __shared__ float sm[3840];   // 15360 B union buffer (l3 layout is the max)
    const int which = blockIdx.y;
    if (which == 0) {
        pool_big_body<4, 0>(U3, 0.5f, Wout + 3072, msp, shq, rbm,
                            h + HOFFc[3], f3, out + HOFFc[3],
                            offsets, elist, neighbors, sm);
    } else if (which == 1) {
        pool_big_body<3, 32>(U2, 0.57735026918962576f, Wout + 2048, msp, shq, rbm,
                             h + HOFFc[2], f2, out + HOFFc[2],
                             offsets, elist, neighbors, sm);
    } else {
        pool_01_body(U1, Wout, msp, shq, rbm, h, f0, f1, out,
                     offsets, elist, neighbors, sm);
    }
}

// =====================================================================
extern "C" void kernel_launch(void* const* d_in, const int* in_sizes, int n_in,
                              void* d_out, int out_size, void* d_ws, size_t ws_size,
                              hipStream_t stream)
{
    (void)in_sizes; (void)n_in; (void)out_size;

    const float* rb     = (const float*)d_in[0];
    const float* sh0    = (const float*)d_in[1];
    const float* sh1    = (const float*)d_in[2];
    const float* sh2    = (const float*)d_in[3];
    const float* sh3    = (const float*)d_in[4];
    const float* f0     = (const float*)d_in[5];
    const float* f1     = (const float*)d_in[6];
    const float* f2     = (const float*)d_in[7];
    const float* f3     = (const float*)d_in[8];
    const float* U1     = (const float*)d_in[9];
    const float* U2     = (const float*)d_in[10];
    const float* U3     = (const float*)d_in[11];
    const float* gammas = (const float*)d_in[12];
    const float* Win    = (const float*)d_in[13];
    const float* Wout   = (const float*)d_in[14];
    const float* A      = (const float*)d_in[15];
    const float* B0     = (const float*)d_in[16];
    const float* B1     = (const float*)d_in[17];
    const float* B2     = (const float*)d_in[18];
    const float* B3     = (const float*)d_in[19];
    const float* msp    = (const float*)d_in[20];
    const int* centers   = (const int*)d_in[21];
    const int* neighbors = (const int*)d_in[22];

    // ws layout (bytes): h bf16 | rbm bf16 | shq f32 | BT | AT | WinT | ints
    const size_t OFF_RBM = 42240000;
    const size_t OFF_SHQ = 93440000;
    const size_t OFF_BT  = 98560000;
    const size_t OFF_AT  = 98641920;
    const size_t OFF_WT  = 98674688;
    const size_t OFF_INT = 98682880;
    const size_t needed  = OFF_INT + (size_t)140001 * 4;
    if (ws_size < needed) return;

    ushort_t* h_bf  = (ushort_t*)d_ws;
    ushort_t* rbm   = (ushort_t*)((char*)d_ws + OFF_RBM);
    float*    shq   = (float*)((char*)d_ws + OFF_SHQ);
    ushort_t* BT    = (ushort_t*)((char*)d_ws + OFF_BT);
    ushort_t* ATb   = (ushort_t*)((char*)d_ws + OFF_AT);
    ushort_t* WinTb = (ushort_t*)((char*)d_ws + OFF_WT);
    int* ibase   = (int*)((char*)d_ws + OFF_INT);
    int* offsets = ibase;            // 20001
    int* counts  = ibase + 20001;    // 20000
    int* cursor  = ibase + 40001;    // 20000
    int* elist   = ibase + 60001;    // 80000

    hipMemsetAsync(counts, 0, (size_t)40000 * sizeof(int), stream);  // counts + cursor

    k_hist_prep<<<553, 256, 0, stream>>>(centers, counts, B0, B1, B2, B3, A, Win,
                                         BT, ATb, WinTb);
    k_scan<<<1, 1024, 0, stream>>>(counts, offsets);
    k_fill<<<313, 256, 0, stream>>>(centers, offsets, cursor, elist);

    k_ne<<<15358, 256, 0, stream>>>(rb, sh0, sh1, sh2, sh3, f0, f1, f2, f3,
                                    gammas, BT, ATb, WinTb, rbm, shq, h_bf);

    dim3 gP(5000, 3);
    k_pools<<<gP, 256, 0, stream>>>(U1, U2, U3, Wout, msp, shq, rbm, h_bf,
                                    f0, f1, f2, f3, (float*)d_out,
                                    offsets, elist, neighbors);
}

// Round 16
// 279.747 us; speedup vs baseline: 1.1530x; 1.1530x over previous
//
#include <hip/hip_runtime.h>
#include <cstdint>

#define NA 20000
#define NE 80000

typedef __attribute__((ext_vector_type(8))) short short8;
typedef __attribute__((ext_vector_type(4))) float f32x4;
typedef unsigned short ushort_t;

// per-l offsets (in ELEMENTS) inside h / out buffers (atom-major, [n][i][j][c])
constexpr int HOFFc[4]   = {0, 2560000, 5120000, 10880000};
// packed rbm layout per edge: rbm0[128] rbm1[96] rbm2[64] rbm3[32]  (320 total)
constexpr int RBMOFFc[4] = {0, 128, 224, 288};

__device__ __forceinline__ ushort_t f2bf(float x) {
    union { float f; unsigned u; } v; v.f = x;
    unsigned r = v.u + 0x7fffu + ((v.u >> 16) & 1u);
    return (ushort_t)(r >> 16);
}
__device__ __forceinline__ float bf2f(ushort_t u) {
    union { unsigned u; float f; } v; v.u = ((unsigned)u) << 16;
    return v.f;
}
__device__ __forceinline__ unsigned pack2(float a, float b) {
    return ((unsigned)f2bf(b) << 16) | (unsigned)f2bf(a);
}

// ---------------- fused: edge-histogram + one-time weight prep ----------------
__global__ __launch_bounds__(256)
void k_hist_prep(const int* __restrict__ centers, int* __restrict__ counts,
                 const float* __restrict__ B0, const float* __restrict__ B1,
                 const float* __restrict__ B2, const float* __restrict__ B3,
                 const float* __restrict__ A, const float* __restrict__ Win,
                 ushort_t* __restrict__ BT, ushort_t* __restrict__ ATb,
                 ushort_t* __restrict__ WinTb)
{
    const int b = blockIdx.x;
    if (b < 313) {
        const int e = b * 256 + threadIdx.x;
        if (e < NE) atomicAdd(&counts[centers[e]], 1);
        return;
    }
    const int i = (b - 313) * 256 + threadIdx.x;
    if (i < 40960) {
        const int n = i >> 7, k = i & 127;
        const float* src; int nl, N;
        if (n < 128)      { src = B0; nl = n;       N = 128; }
        else if (n < 224) { src = B1; nl = n - 128; N = 96;  }
        else if (n < 288) { src = B2; nl = n - 224; N = 64;  }
        else              { src = B3; nl = n - 288; N = 32;  }
        BT[i] = f2bf(src[k * N + nl]);
    } else if (i < 57344) {
        const int j2 = i - 40960;
        const int l = j2 >> 12, rem = j2 & 4095, jrow = rem >> 5, k = rem & 31;
        ATb[j2] = f2bf(A[l * 4096 + k * 128 + jrow]);
    } else if (i < 61440) {
        const int j3 = i - 57344;
        const int l = j3 >> 10, rem = j3 & 1023, g = rem >> 5, k = rem & 31;
        WinTb[j3] = f2bf(Win[l * 1024 + k * 32 + g]);
    }
}

// ---------------- Kernel 1: RMSNorm + linear_in via MFMA -> h (bf16) ----------------
template<int S, int AB>
__device__ __forceinline__ void norm_body(
    const float* __restrict__ fsel, const float* __restrict__ gammas, int l,
    const ushort_t* __restrict__ WinTb, ushort_t* __restrict__ hb,
    ushort_t* __restrict__ s_wt, float* __restrict__ s_scale)
{
    const int t = threadIdx.x;
    const int na0 = blockIdx.x * AB;

    if (t < 128) {
        reinterpret_cast<uint4*>(s_wt)[t] =
            reinterpret_cast<const uint4*>(WinTb + l * 1024)[t];
    }
    for (int i = t; i < AB * 32; i += 256) {
        const int a = i >> 5, c = i & 31;
        int aa = na0 + a; if (aa > NA - 1) aa = NA - 1;
        const float* fp = fsel + ((size_t)aa * S) * 32 + c;
        float ss = 0.f;
        #pragma unroll
        for (int s = 0; s < S; ++s) { const float v = fp[s * 32]; ss += v * v; }
        s_scale[i] = gammas[l * 32 + c] * rsqrtf(ss / (float)S + 1e-6f);
    }
    __syncthreads();

    const int w = t >> 6, lane = t & 63, l15 = lane & 15, lg = lane >> 4;
    const int row = w * 16 + l15;
    const bool rvalid = row < AB * S;
    const int rowc = rvalid ? row : 0;
    const int a = rowc / S, s = rowc % S;
    const int atom = na0 + a;
    const bool store_ok = rvalid && (atom < NA);
    const int atomc = (atom < NA) ? atom : (NA - 1);

    const float* fp = fsel + ((size_t)atomc * S + s) * 32 + lg * 8;
    const float4 x0 = *reinterpret_cast<const float4*>(fp);
    const float4 x1 = *reinterpret_cast<const float4*>(fp + 4);
    const float4 c0 = *reinterpret_cast<const float4*>(&s_scale[a * 32 + lg * 8]);
    const float4 c1 = *reinterpret_cast<const float4*>(&s_scale[a * 32 + lg * 8 + 4]);

    union { short8 v; unsigned u[4]; } bf;
    bf.u[0] = pack2(x0.x * c0.x, x0.y * c0.y);
    bf.u[1] = pack2(x0.z * c0.z, x0.w * c0.w);
    bf.u[2] = pack2(x1.x * c1.x, x1.y * c1.y);
    bf.u[3] = pack2(x1.z * c1.z, x1.w * c1.w);

    const short8 a0 = *reinterpret_cast<const short8*>(&s_wt[l15 * 32 + lg * 8]);
    const short8 a1 = *reinterpret_cast<const short8*>(&s_wt[(16 + l15) * 32 + lg * 8]);
    f32x4 d0 = __builtin_amdgcn_mfma_f32_16x16x32_bf16(a0, bf.v, (f32x4){0.f,0.f,0.f,0.f}, 0, 0, 0);
    f32x4 d1 = __builtin_amdgcn_mfma_f32_16x16x32_bf16(a1, bf.v, (f32x4){0.f,0.f,0.f,0.f}, 0, 0, 0);

    if (store_ok) {
        ushort_t* hp = hb + ((size_t)atomc * S + s) * 32;
        uint2 o0; o0.x = pack2(d0[0], d0[1]); o0.y = pack2(d0[2], d0[3]);
        uint2 o1; o1.x = pack2(d1[0], d1[1]); o1.y = pack2(d1[2], d1[3]);
        *reinterpret_cast<uint2*>(&hp[0  + 4 * lg]) = o0;
        *reinterpret_cast<uint2*>(&hp[16 + 4 * lg]) = o1;
    }
}

__global__ __launch_bounds__(256, 8)
void k_norm_mfma(const float* __restrict__ f0, const float* __restrict__ f1,
                 const float* __restrict__ f2, const float* __restrict__ f3,
                 const float* __restrict__ gammas, const ushort_t* __restrict__ WinTb,
                 ushort_t* __restrict__ h)
{
    __shared__ ushort_t s_wt[1024];
    __shared__ float s_scale[512];
    const int l = blockIdx.y;
    if (l == 0) {
        if (blockIdx.x >= 1250) return;
        norm_body<4, 16>(f0, gammas, 0, WinTb, h + HOFFc[0], s_wt, s_scale);
    } else if (l == 1) {
        if (blockIdx.x >= 1250) return;
        norm_body<4, 16>(f1, gammas, 1, WinTb, h + HOFFc[1], s_wt, s_scale);
    } else if (l == 2) {
        if (blockIdx.x >= 2858) return;
        norm_body<9, 7>(f2, gammas, 2, WinTb, h + HOFFc[2], s_wt, s_scale);
    } else {
        norm_body<16, 4>(f3, gammas, 3, WinTb, h + HOFFc[3], s_wt, s_scale);
    }
}

// ---------------- Kernel 2: radial MLP, both phases MFMA; one l per block ----------------
__global__ __launch_bounds__(256, 3)
void k_edgeA(const float* __restrict__ rb,
             const float* __restrict__ sh0, const float* __restrict__ sh1,
             const float* __restrict__ sh2, const float* __restrict__ sh3,
             const ushort_t* __restrict__ BT, const ushort_t* __restrict__ ATb,
             ushort_t* __restrict__ rbm, float* __restrict__ shq)
{
    __shared__ ushort_t s_h[8192];    // 16 KB [64][128] bf16, chunk ^= (row&7)
    __shared__ ushort_t s_r2[16384];  // 32 KB
    ushort_t* s_rbbf = s_r2;          // [64][32]  (phase1)
    ushort_t* s_at   = s_r2 + 2048;   // [128][32] (phase1)
    ushort_t* s_bt   = s_r2;          // [N_l][128] swizzled (phase2)

    const int t  = threadIdx.x;
    const int e0 = blockIdx.x * 64;
    const int l  = blockIdx.y;
    const int w  = t >> 6, lane = t & 63;
    const int l15 = lane & 15, lg = lane >> 4;

    if (l == 0) {
        for (int i = t; i < 1024; i += 256) {
            const int q = i & 15, ge = e0 + (i >> 4);
            float v;
            if (q == 0)      v = sh0[ge];
            else if (q < 4)  v = sh1[ge * 3 + (q - 1)];
            else if (q < 9)  v = sh2[ge * 5 + (q - 4)];
            else             v = sh3[ge * 7 + (q - 9)];
            shq[(size_t)e0 * 16 + i] = v;
        }
    }

    const int Kl[4] = {128, 96, 64, 32};
    const int erow = w * 16 + l15;

    for (int i = t; i < 1024; i += 256) {
        const float2 v = *reinterpret_cast<const float2*>(
            &rb[(size_t)l * NE * 32 + (size_t)e0 * 32 + 2 * i]);
        *reinterpret_cast<unsigned*>(&s_rbbf[2 * i]) = pack2(v.x, v.y);
    }
    {
        const uint4* src = reinterpret_cast<const uint4*>(ATb + (size_t)l * 4096);
        for (int i = t; i < 512; i += 256) reinterpret_cast<uint4*>(s_at)[i] = src[i];
    }
    __syncthreads();

    // phase1 MFMA: hid = rb @ A_l -> s_h (swizzled bf16)
    const short8 rbf = *reinterpret_cast<const short8*>(&s_rbbf[erow * 32 + lg * 8]);
    #pragma unroll
    for (int jt = 0; jt < 8; ++jt) {
        const short8 af = *reinterpret_cast<const short8*>(&s_at[(jt * 16 + l15) * 32 + lg * 8]);
        f32x4 d = __builtin_amdgcn_mfma_f32_16x16x32_bf16(af, rbf, (f32x4){0.f,0.f,0.f,0.f}, 0, 0, 0);
        float s0 = d[0] / (1.f + __expf(-d[0]));
        float s1 = d[1] / (1.f + __expf(-d[1]));
        float s2 = d[2] / (1.f + __expf(-d[2]));
        float s3 = d[3] / (1.f + __expf(-d[3]));
        const int chunk = jt * 2 + (lg >> 1);
        const int base = erow * 128 + ((chunk ^ (erow & 7)) << 3) + (lg & 1) * 4;
        uint2 ov; ov.x = pack2(s0, s1); ov.y = pack2(s2, s3);
        *reinterpret_cast<uint2*>(&s_h[base]) = ov;
    }
    __syncthreads();

    // stage B^T_l
    const int K = Kl[l];
    for (int cch = t; cch < (K << 4); cch += 256) {
        const int n = cch >> 4, loc = cch & 15;
        const uint4 v = *reinterpret_cast<const uint4*>(&BT[(size_t)(RBMOFFc[l] + n) * 128 + loc * 8]);
        *reinterpret_cast<uint4*>(&s_bt[n * 128 + ((loc ^ (n & 7)) << 3)]) = v;
    }
    __syncthreads();

    // phase2 MFMA: rbm[e][n]
    const short8 hf0 = *reinterpret_cast<const short8*>(&s_h[erow * 128 + (((0 + lg) ^ (erow & 7)) << 3)]);
    const short8 hf1 = *reinterpret_cast<const short8*>(&s_h[erow * 128 + (((4 + lg) ^ (erow & 7)) << 3)]);
    const short8 hf2 = *reinterpret_cast<const short8*>(&s_h[erow * 128 + (((8 + lg) ^ (erow & 7)) << 3)]);
    const short8 hf3 = *reinterpret_cast<const short8*>(&s_h[erow * 128 + (((12 + lg) ^ (erow & 7)) << 3)]);

    const int ntn = K >> 4;
    for (int nt = 0; nt < ntn; ++nt) {
        const int n = nt * 16 + l15;
        f32x4 acc = {0.f, 0.f, 0.f, 0.f};
        #pragma unroll
        for (int ks = 0; ks < 4; ++ks) {
            const short8 af = *reinterpret_cast<const short8*>(
                &s_bt[n * 128 + (((ks * 4 + lg) ^ (n & 7)) << 3)]);
            const short8 hfk = (ks == 0) ? hf0 : (ks == 1) ? hf1 : (ks == 2) ? hf2 : hf3;
            acc = __builtin_amdgcn_mfma_f32_16x16x32_bf16(af, hfk, acc, 0, 0, 0);
        }
        uint2 ov;
        ov.x = pack2(acc[0], acc[1]);
        ov.y = pack2(acc[2], acc[3]);
        *reinterpret_cast<uint2*>(&rbm[(size_t)(e0 + erow) * 320 + RBMOFFc[l] + nt * 16 + 4 * lg]) = ov;
    }
}

// ---------------- CSR scan + fill ----------------
__global__ __launch_bounds__(1024)
void k_scan(const int* __restrict__ counts, int* __restrict__ offsets)
{
    __shared__ int s_sum[1024];
    const int t = threadIdx.x;
    const int CH = 20;
    const int base = t * CH;
    int n = NA - base; n = n < 0 ? 0 : (n > CH ? CH : n);

    int tot = 0;
    for (int i = 0; i < n; i++) tot += counts[base + i];
    s_sum[t] = tot;
    __syncthreads();
    for (int off = 1; off < 1024; off <<= 1) {
        int v = (t >= off) ? s_sum[t - off] : 0;
        __syncthreads();
        s_sum[t] += v;
        __syncthreads();
    }
    int run = s_sum[t] - tot;
    for (int i = 0; i < n; i++) { offsets[base + i] = run; run += counts[base + i]; }
    if (t == 0) offsets[NA] = NE;
}

__global__ __launch_bounds__(256)
void k_fill(const int* __restrict__ centers, const int* __restrict__ offsets,
            int* __restrict__ cursor, int* __restrict__ elist)
{
    const int e = blockIdx.x * 256 + threadIdx.x;
    if (e < NE) {
        const int ctr = centers[e];
        const int pos = offsets[ctr] + atomicAdd(&cursor[ctr], 1);
        elist[pos] = e;
    }
}

// ---------------- TP step (bf16 LDS h), all register indices compile-time ----------------
template<int P1, int ASTART, int ACNT>
__device__ __forceinline__ void tp_step(float* __restrict__ acc,
                                        const float* __restrict__ lg,
                                        const ushort_t* __restrict__ lh,
                                        const float* __restrict__ rv, int c)
{
    float un[ACNT];
    #pragma unroll
    for (int pi = 0; pi < ACNT; ++pi) {
        const int p = ASTART + pi;
        float a = 0.f;
        #pragma unroll
        for (int lp = 0; lp < P1; ++lp) a += lg[p * 4 + lp] * rv[lp];
        un[pi] = a;
    }
    #pragma unroll
    for (int ii = 0; ii < ACNT / P1; ++ii) {
        #pragma unroll
        for (int k = 0; k < P1; ++k) {
            float m = 0.f;
            #pragma unroll
            for (int j = 0; j < P1; ++j) m += un[ii * P1 + j] * bf2f(lh[(j * P1 + k) * 32 + c]);
            acc[ii * P1 + k] += m;
        }
    }
}

// ---------------- pool body: l2/l3 (paired edges), carving union LDS ----------------
template<int P1, int LOWER>
__device__ __forceinline__ void pool_big_body(
    const float* __restrict__ Up, float uscale,
    const float* __restrict__ WoutL, const float* __restrict__ msp,
    const float* __restrict__ shq, const ushort_t* __restrict__ rbm,
    const ushort_t* __restrict__ hL, const float* __restrict__ fL,
    float* __restrict__ outL,
    const int* __restrict__ offsets, const int* __restrict__ elist,
    const int* __restrict__ neighbors, float* __restrict__ sm)
{
    constexpr int S       = P1 * P1;
    constexpr int ACNT0   = (P1 == 4) ? 8 : 6;
    constexpr int ACNT1   = (P1 == 4) ? 8 : 3;
    constexpr int ASTART1 = ACNT0;
    constexpr int NV      = (S * 32) / 8;

    float*    s_U    = sm;
    float*    s_w    = sm + 256;
    ushort_t* s_hbuf = reinterpret_cast<ushort_t*>(sm + 256 + 1024);
    float*    s_gbuf = sm + 256 + 1024 + 128 * S;   // 8 bufs of S*32 ushorts = 128*S floats

    const int t = threadIdx.x;
    for (int i = t; i < S * S; i += 256) s_U[i] = Up[i] * uscale;
    for (int i = t; i < 1024; i += 256) s_w[i] = WoutL[i];
    __syncthreads();

    const int w = t >> 6, lane = t & 63, c = lane & 31, half = lane >> 5;
    const int n = blockIdx.x * 4 + w;
    const float ms = *msp;
    const int beg = offsets[n], end = offsets[n + 1];

    const int gp = lane >> 2, glp = lane & 3;
    const int qlo = (glp == 0) ? 0 : (glp == 1) ? 1 : (glp == 2) ? 4 : 9;
    const int qhi = (glp == 0) ? 1 : (glp == 1) ? 4 : (glp == 2) ? 9 : 16;
    const bool gvalid = (gp < S) && (glp < P1);

    float acc[ACNT0];
    #pragma unroll
    for (int x = 0; x < ACNT0; ++x) acc[x] = 0.f;

    ushort_t* lhA = s_hbuf + w * 2 * (S * 32);
    ushort_t* lhB = lhA + S * 32;
    float*    lgA = s_gbuf + w * 128;
    float*    lgB = lgA + 64;

    for (int slot = beg; slot < end; slot += 2) {
        const bool haveB = (slot + 1) < end;
        const int eA = elist[slot];
        const int eB = elist[haveB ? slot + 1 : slot];
        const int nbrA = neighbors[eA];
        const int nbrB = neighbors[eB];

        uint4 vA = {}, vB = {};
        const uint4* hpA = reinterpret_cast<const uint4*>(hL + (size_t)nbrA * (S * 32));
        const uint4* hpB = reinterpret_cast<const uint4*>(hL + (size_t)nbrB * (S * 32));
        if (lane < NV) { vA = hpA[lane]; vB = hpB[lane]; }

        const ushort_t* rrA = rbm + (size_t)eA * 320 + LOWER + c;
        const ushort_t* rrB = rbm + (size_t)eB * 320 + LOWER + c;
        float rvA[4], rvB[4];
        #pragma unroll
        for (int lp = 0; lp < P1; ++lp) { rvA[lp] = bf2f(rrA[RBMOFFc[lp]]); rvB[lp] = bf2f(rrB[RBMOFFc[lp]]); }

        const float* sqA = shq + (size_t)eA * 16;
        const float* sqB = shq + (size_t)eB * 16;
        float gA = 0.f, gB = 0.f;
        if (gvalid) {
            for (int q = qlo; q < qhi; ++q) {
                const float u = s_U[gp * S + q];
                gA += u * sqA[q];
                gB += u * sqB[q];
            }
        }

        if (lane < NV) {
            reinterpret_cast<uint4*>(lhA)[lane] = vA;
            reinterpret_cast<uint4*>(lhB)[lane] = vB;
        }
        lgA[lane] = gA;
        lgB[lane] = gB;

        asm volatile("s_waitcnt lgkmcnt(0)" ::: "memory");

        if (half == 0) tp_step<P1, 0,       ACNT0>(acc, lgA, lhA, rvA, c);
        else           tp_step<P1, ASTART1, ACNT1>(acc, lgA, lhA, rvA, c);
        if (haveB) {
            if (half == 0) tp_step<P1, 0,       ACNT0>(acc, lgB, lhB, rvB, c);
            else           tp_step<P1, ASTART1, ACNT1>(acc, lgB, lhB, rvB, c);
        }
    }

    float* accStage = reinterpret_cast<float*>(lhA);   // spans lhA+lhB = S*32 floats
    if (half == 0) {
        #pragma unroll
        for (int x = 0; x < ACNT0; ++x) accStage[x * 32 + c] = acc[x];
    } else {
        #pragma unroll
        for (int x = 0; x < ACNT1; ++x) accStage[(ASTART1 + x) * 32 + c] = acc[x];
    }
    asm volatile("s_waitcnt lgkmcnt(0)" ::: "memory");

    const float* fp = fL + (size_t)n * (S * 32);
    float* op = outL + (size_t)n * (S * 32);
    for (int s = half; s < S; s += 2) {
        float o = 0.f;
        #pragma unroll
        for (int f = 0; f < 32; f++) o += accStage[s * 32 + f] * s_w[f * 32 + c];
        op[s * 32 + c] = fp[s * 32 + c] + ms * o;
    }
}

// ---------------- pool body: fused l0+l1, carving union LDS ----------------
__device__ __forceinline__ void pool_01_body(
    const float* __restrict__ U1, const float* __restrict__ Wout,
    const float* __restrict__ msp, const float* __restrict__ shq,
    const ushort_t* __restrict__ rbm, const ushort_t* __restrict__ h,
    const float* __restrict__ f0, const float* __restrict__ f1,
    float* __restrict__ out,
    const int* __restrict__ offsets, const int* __restrict__ elist,
    const int* __restrict__ neighbors, float* __restrict__ sm)
{
    float* s_U   = sm;
    float* s_w   = sm + 16;
    float* s_acc = sm + 16 + 2048;

    const int t = threadIdx.x;
    if (t < 16) s_U[t] = U1[t] * 0.70710678118654752f;
    for (int i = t; i < 2048; i += 256) s_w[i] = Wout[i];
    __syncthreads();

    const int w = t >> 6, lane = t & 63, c = lane & 31, half = lane >> 5;
    const int n = blockIdx.x * 4 + w;
    const float ms = *msp;
    const int beg = offsets[n], end = offsets[n + 1];
    const ushort_t* h0 = h;
    const ushort_t* h1 = h + 2560000;

    float acc0[4] = {0.f, 0.f, 0.f, 0.f};
    float acc1[4] = {0.f, 0.f, 0.f, 0.f};

    const int nit = (end - beg + 1) >> 1;
    for (int it = 0; it < nit; ++it) {
        const int slot = beg + it * 2 + half;
        const bool valid = slot < end;
        const int e   = elist[valid ? slot : beg];
        const int nbr = neighbors[e];
        const float fac = valid ? 1.f : 0.f;

        const ushort_t* rrow = rbm + (size_t)e * 320;
        const float rv0  = fac * bf2f(rrow[96 + c]);
        const float rv1a = fac * bf2f(rrow[64 + c]);
        const float rv1b = fac * bf2f(rrow[192 + c]);
        const float* sqp = shq + (size_t)e * 16;
        const float sq0 = sqp[0], sq1 = sqp[1], sq2 = sqp[2], sq3 = sqp[3];

        float hn0[4], hn1[4];
        const ushort_t* hp0 = h0 + (size_t)nbr * 128 + c;
        const ushort_t* hp1 = h1 + (size_t)nbr * 128 + c;
        #pragma unroll
        for (int p = 0; p < 4; ++p) { hn0[p] = bf2f(hp0[p * 32]); hn1[p] = bf2f(hp1[p * 32]); }

        const float st0 = sq0 * rv0;
        float st1[4];
        st1[0] = sq0 * rv1a; st1[1] = sq1 * rv1b; st1[2] = sq2 * rv1b; st1[3] = sq3 * rv1b;

        float unc0[4], unc1[4];
        #pragma unroll
        for (int p = 0; p < 4; ++p) {
            unc0[p] = s_U[p * 4] * st0;
            float a = 0.f;
            #pragma unroll
            for (int q = 0; q < 4; ++q) a += s_U[p * 4 + q] * st1[q];
            unc1[p] = a;
        }
        #pragma unroll
        for (int i = 0; i < 2; ++i) {
            #pragma unroll
            for (int k = 0; k < 2; ++k) {
                float m0 = 0.f, m1 = 0.f;
                #pragma unroll
                for (int j = 0; j < 2; ++j) {
                    m0 += unc0[i * 2 + j] * hn0[j * 2 + k];
                    m1 += unc1[i * 2 + j] * hn1[j * 2 + k];
                }
                acc0[i * 2 + k] += m0;
                acc1[i * 2 + k] += m1;
            }
        }
    }

    #pragma unroll
    for (int s = 0; s < 4; s++) { acc0[s] += __shfl_xor(acc0[s], 32); acc1[s] += __shfl_xor(acc1[s], 32); }
    #pragma unroll
    for (int s = 0; s < 4; s++) if ((s & 1) == half) {
        s_acc[(w * 2 + 0) * 128 + s * 32 + c] = acc0[s];
        s_acc[(w * 2 + 1) * 128 + s * 32 + c] = acc1[s];
    }
    __syncthreads();

    const float* fp0 = f0 + (size_t)n * 128;
    const float* fp1 = f1 + (size_t)n * 128;
    float* op0 = out + (size_t)n * 128;
    float* op1 = out + 2560000 + (size_t)n * 128;
    for (int s = half; s < 4; s += 2) {
        float o0 = 0.f, o1 = 0.f;
        #pragma unroll
        for (int f = 0; f < 32; f++) {
            o0 += s_acc[(w * 2 + 0) * 128 + s * 32 + f] * s_w[f * 32 + c];
            o1 += s_acc[(w * 2 + 1) * 128 + s * 32 + f] * s_w[1024 + f * 32 + c];
        }
        op0[s * 32 + c] = fp0[s * 32 + c] + ms * o0;
        op1[s * 32 + c] = fp1[s * 32 + c] + ms * o1;
    }
}

// ---------------- ONE pool dispatch: blockIdx.y selects {l3, l2, l0+l1} ----------------
__global__ __launch_bounds__(256, 6)
void k_pools(const float* __restrict__ U1, const float* __restrict__ U2,
             const float* __restrict__ U3, const float* __restrict__ Wout,
             const float* __restrict__ msp, const float* __restrict__ shq,
             const ushort_t* __restrict__ rbm, const ushort_t* __restrict__ h,
             const float* __restrict__ f0, const float* __restrict__ f1,
             const float* __restrict__ f2, const float* __restrict__ f3,
             float* __restrict__ out,
             const int* __restrict__ offsets, const int* __restrict__ elist,
             const int* __restrict__ neighbors)
{
    __shared__ float sm[3840];   // 15360 B union buffer (l3 layout is the max)
    const int which = blockIdx.y;
    if (which == 0) {
        pool_big_body<4, 0>(U3, 0.5f, Wout + 3072, msp, shq, rbm,
                            h + HOFFc[3], f3, out + HOFFc[3],
                            offsets, elist, neighbors, sm);
    } else if (which == 1) {
        pool_big_body<3, 32>(U2, 0.57735026918962576f, Wout + 2048, msp, shq, rbm,
                             h + HOFFc[2], f2, out + HOFFc[2],
                             offsets, elist, neighbors, sm);
    } else {
        pool_01_body(U1, Wout, msp, shq, rbm, h, f0, f1, out,
                     offsets, elist, neighbors, sm);
    }
}

// =====================================================================
extern "C" void kernel_launch(void* const* d_in, const int* in_sizes, int n_in,
                              void* d_out, int out_size, void* d_ws, size_t ws_size,
                              hipStream_t stream)
{
    (void)in_sizes; (void)n_in; (void)out_size;

    const float* rb     = (const float*)d_in[0];
    const float* sh0    = (const float*)d_in[1];
    const float* sh1    = (const float*)d_in[2];
    const float* sh2    = (const float*)d_in[3];
    const float* sh3    = (const float*)d_in[4];
    const float* f0     = (const float*)d_in[5];
    const float* f1     = (const float*)d_in[6];
    const float* f2     = (const float*)d_in[7];
    const float* f3     = (const float*)d_in[8];
    const float* U1     = (const float*)d_in[9];
    const float* U2     = (const float*)d_in[10];
    const float* U3     = (const float*)d_in[11];
    const float* gammas = (const float*)d_in[12];
    const float* Win    = (const float*)d_in[13];
    const float* Wout   = (const float*)d_in[14];
    const float* A      = (const float*)d_in[15];
    const float* B0     = (const float*)d_in[16];
    const float* B1     = (const float*)d_in[17];
    const float* B2     = (const float*)d_in[18];
    const float* B3     = (const float*)d_in[19];
    const float* msp    = (const float*)d_in[20];
    const int* centers   = (const int*)d_in[21];
    const int* neighbors = (const int*)d_in[22];

    // ws layout (bytes): h bf16 | rbm bf16 | shq f32 | BT | AT | WinT | ints
    const size_t OFF_RBM = 42240000;
    const size_t OFF_SHQ = 93440000;
    const size_t OFF_BT  = 98560000;
    const size_t OFF_AT  = 98641920;
    const size_t OFF_WT  = 98674688;
    const size_t OFF_INT = 98682880;
    const size_t needed  = OFF_INT + (size_t)140001 * 4;
    if (ws_size < needed) return;

    ushort_t* h_bf  = (ushort_t*)d_ws;
    ushort_t* rbm   = (ushort_t*)((char*)d_ws + OFF_RBM);
    float*    shq   = (float*)((char*)d_ws + OFF_SHQ);
    ushort_t* BT    = (ushort_t*)((char*)d_ws + OFF_BT);
    ushort_t* ATb   = (ushort_t*)((char*)d_ws + OFF_AT);
    ushort_t* WinTb = (ushort_t*)((char*)d_ws + OFF_WT);
    int* ibase   = (int*)((char*)d_ws + OFF_INT);
    int* offsets = ibase;            // 20001
    int* counts  = ibase + 20001;    // 20000
    int* cursor  = ibase + 40001;    // 20000
    int* elist   = ibase + 60001;    // 80000

    hipMemsetAsync(counts, 0, (size_t)40000 * sizeof(int), stream);  // counts + cursor

    k_hist_prep<<<553, 256, 0, stream>>>(centers, counts, B0, B1, B2, B3, A, Win,
                                         BT, ATb, WinTb);
    k_scan<<<1, 1024, 0, stream>>>(counts, offsets);
    k_fill<<<313, 256, 0, stream>>>(centers, offsets, cursor, elist);

    dim3 gN(5000, 4);
    k_norm_mfma<<<gN, 256, 0, stream>>>(f0, f1, f2, f3, gammas, WinTb, h_bf);
    dim3 gE(1250, 4);
    k_edgeA<<<gE, 256, 0, stream>>>(rb, sh0, sh1, sh2, sh3, BT, ATb, rbm, shq);

    dim3 gP(5000, 3);
    k_pools<<<gP, 256, 0, stream>>>(U1, U2, U3, Wout, msp, shq, rbm, h_bf,
                                    f0, f1, f2, f3, (float*)d_out,
                                    offsets, elist, neighbors);
}